// Round 6
// baseline (359.926 us; speedup 1.0000x reference)
//
#include <hip/hip_runtime.h>
#include <stdint.h>

// PixCorr: per-row Pearson corr of preds vs targets, mean over 256 rows.
// fp32, D=3*256*256=196608/row; 402.7 MB streamed once; floor ~60us @6.9TB/s.
// R6: (1) drop __syncthreads entirely in the hot loop -- each wave's DMAs
// land only in its own LDS quarter and are read back only by that wave, so
// a per-wave `s_waitcnt vmcnt(0)` suffices; waves free-run, no block-wide
// lockstep through HBM latency. (2) amortize the reduce epilogue: 1024
// blocks (exactly 4/CU co-resident, 128KiB LDS/CU), each looping 12 chunks
// with register accumulators, one epilogue at the end. (3) merged finish.

typedef float f4 __attribute__((ext_vector_type(4)));

constexpr int NROWS = 256;
constexpr int D     = 3 * 256 * 256;     // 196608 floats per row
constexpr int D4    = D / 4;             // 49152 float4 per row
constexpr int TPB   = 256;               // 4 waves per block
constexpr int BATCH = 4;                 // float4 pairs per thread per iter
constexpr int C4    = TPB * BATCH;       // 1024 float4 per iter per block
constexpr int SLOTS = 4;                 // blocks per row
constexpr int ITERS = D4 / (SLOTS * C4); // 12 iters per block
constexpr double EPS = 1e-6;

__device__ __forceinline__ void async_ld16(const void* g, void* l) {
    // aux=2: nt cache policy (no L2/L3 allocation thrash -- R3's win).
    __builtin_amdgcn_global_load_lds(
        (const __attribute__((address_space(1))) uint32_t*)g,
        (__attribute__((address_space(3))) uint32_t*)l,
        16, 0, 2);
}

// ws layout: partials[1024][5] doubles = 40 KiB.
__global__ __launch_bounds__(TPB) void partial_kernel(
        const f4* __restrict__ preds,
        const f4* __restrict__ targets,
        double* __restrict__ partials)
{
    __shared__ f4 sBuf[2][BATCH][TPB];   // 32 KiB; wave w owns [..][w*64..w*64+63]

    const int  blk  = blockIdx.x;
    const int  row  = blk / SLOTS;
    const int  slot = blk % SLOTS;
    const int  tid  = threadIdx.x;
    const int  w    = tid >> 6;          // wave id (lane-uniform)
    const int  lane = tid & 63;
    const long base0 = (long)row * D4 + (long)slot * (ITERS * C4);

    double sZ = 0.0, sB = 0.0, sZZ = 0.0, sBB = 0.0, sZB = 0.0;

    for (int i = 0; i < ITERS; ++i) {
        const long base = base0 + (long)i * C4;
        // Issue 8 DMAs back-to-back (no dest VGPR -> cannot be serialized).
        #pragma unroll
        for (int u = 0; u < BATCH; ++u) {
            const long gi = base + u * TPB + tid;
            async_ld16(&preds[gi],   &sBuf[0][u][w * 64]);
            async_ld16(&targets[gi], &sBuf[1][u][w * 64]);
        }
        // Per-wave drain only -- no barrier, waves free-run.
        asm volatile("s_waitcnt vmcnt(0)" ::: "memory");

        #pragma unroll
        for (int u = 0; u < BATCH; ++u) {
            const f4 b4 = sBuf[0][u][tid];   // own wave's quarter only
            const f4 z4 = sBuf[1][u][tid];
            double z, b;
            z = (double)z4.x; b = (double)b4.x;
            sZ += z; sB += b; sZZ = fma(z,z,sZZ); sBB = fma(b,b,sBB); sZB = fma(z,b,sZB);
            z = (double)z4.y; b = (double)b4.y;
            sZ += z; sB += b; sZZ = fma(z,z,sZZ); sBB = fma(b,b,sBB); sZB = fma(z,b,sZB);
            z = (double)z4.z; b = (double)b4.z;
            sZ += z; sB += b; sZZ = fma(z,z,sZZ); sBB = fma(b,b,sBB); sZB = fma(z,b,sZB);
            z = (double)z4.w; b = (double)b4.w;
            sZ += z; sB += b; sZZ = fma(z,z,sZZ); sBB = fma(b,b,sBB); sZB = fma(z,b,sZB);
        }
    }

    // Epilogue (once per block): wave shuffle reduce, cross-wave via LDS.
    #pragma unroll
    for (int off = 32; off > 0; off >>= 1) {
        sZ  += __shfl_down(sZ,  off);
        sB  += __shfl_down(sB,  off);
        sZZ += __shfl_down(sZZ, off);
        sBB += __shfl_down(sBB, off);
        sZB += __shfl_down(sZB, off);
    }

    __shared__ double sm[5][TPB / 64];
    if (lane == 0) {
        sm[0][w] = sZ;  sm[1][w] = sB;
        sm[2][w] = sZZ; sm[3][w] = sBB;
        sm[4][w] = sZB;
    }
    __syncthreads();
    if (tid == 0) {
        double* out = partials + (long)blk * 5;
        #pragma unroll
        for (int k = 0; k < 5; ++k)
            out[k] = sm[k][0] + sm[k][1] + sm[k][2] + sm[k][3];
    }
}

// One block, 256 threads: thread r sums its row's 4 slot-partials, computes
// corr_r, then block-reduces the mean. (Merged former stages 2+3.)
__global__ __launch_bounds__(NROWS) void finish_kernel(
        const double* __restrict__ partials, float* __restrict__ out)
{
    const int r = threadIdx.x;
    double tZ = 0, tB = 0, tZZ = 0, tBB = 0, tZB = 0;
    #pragma unroll
    for (int s = 0; s < SLOTS; ++s) {
        const double* p = partials + ((long)r * SLOTS + s) * 5;
        tZ += p[0]; tB += p[1]; tZZ += p[2]; tBB += p[3]; tZB += p[4];
    }
    const double invD = 1.0 / (double)D;
    const double num  = tZB - tZ * tB * invD;
    const double varZ = fmax(tZZ - tZ * tZ * invD, 0.0);
    const double varB = fmax(tBB - tB * tB * invD, 0.0);
    const double den  = sqrt(varZ) * sqrt(varB) + EPS;
    double v = num / den;

    #pragma unroll
    for (int off = 32; off > 0; off >>= 1) v += __shfl_down(v, off);

    __shared__ double sm[NROWS / 64];
    const int wave = r >> 6;
    const int lane = r & 63;
    if (lane == 0) sm[wave] = v;
    __syncthreads();
    if (r == 0) {
        double t = 0.0;
        #pragma unroll
        for (int w = 0; w < NROWS / 64; ++w) t += sm[w];
        out[0] = (float)(t / (double)NROWS);
    }
}

extern "C" void kernel_launch(void* const* d_in, const int* in_sizes, int n_in,
                              void* d_out, int out_size, void* d_ws, size_t ws_size,
                              hipStream_t stream) {
    const f4* preds   = (const f4*)d_in[0];
    const f4* targets = (const f4*)d_in[1];
    double* partials = (double*)d_ws;   // 1024 * 5 doubles = 40 KiB
    float*  out      = (float*)d_out;

    hipLaunchKernelGGL(partial_kernel, dim3(NROWS * SLOTS), dim3(TPB), 0, stream,
                       preds, targets, partials);
    hipLaunchKernelGGL(finish_kernel, dim3(1), dim3(NROWS), 0, stream,
                       partials, out);
}